// Round 1
// baseline (102.648 us; speedup 1.0000x reference)
//
#include <hip/hip_runtime.h>
#include <hip/hip_bf16.h>

// Hopf oscillator scan: B=32, T=1000, D=512.
// One thread per (b,d) chain; 1000 sequential steps per thread.
// carry (r, phi); one sincos per step (reused for output t and input t+1).

#define B 32
#define T 1000
#define D 512
#define DT 0.001f
#define K_IN (5.0f * DT)          // INPUT_SCALER * DT
#define TWO_PI 6.283185307179586f

__global__ __launch_bounds__(64) void hopf_scan(
    const float* __restrict__ Xr, const float* __restrict__ Xi,
    const float* __restrict__ om,
    float* __restrict__ zr, float* __restrict__ zi) {
    const int tid = blockIdx.x * 64 + threadIdx.x;   // 0..16383
    const int b = tid >> 9;                          // /D
    const int d = tid & (D - 1);

    // omega in rad/s, premultiplied by DT
    const float omega = (om[d] * 10.0f + 0.1f) * TWO_PI;
    const float od = omega * DT;

    const size_t base = (size_t)b * (T * D) + d;
    const float* __restrict__ xrp = Xr + base;
    const float* __restrict__ xip = Xi + base;
    float* __restrict__ zrp = zr + base;
    float* __restrict__ zip = zi + base;

    float r = 1.0f;
    float phi = 0.0f;
    float c = 1.0f;   // cos(phi0)
    float s = 0.0f;   // sin(phi0)

#pragma unroll 8
    for (int t = 0; t < T; ++t) {
        const float xr = xrp[(size_t)t * D];
        const float xi = xip[(size_t)t * D];
        // r_{t+1} = r + ((1 - r^2) * r) * DT + K_IN * xr * cos(phi_old)
        r = r + ((1.0f - r * r) * r) * DT + K_IN * xr * c;
        // phi_{t+1} = phi + omega*DT - K_IN * xi * sin(phi_old)
        phi = phi + od - K_IN * xi * s;
        // sincos(phi_new): used for this step's output AND next step's input
        s = __sinf(phi);
        c = __cosf(phi);
        zrp[(size_t)t * D] = r * c;
        zip[(size_t)t * D] = r * s;
    }
}

extern "C" void kernel_launch(void* const* d_in, const int* in_sizes, int n_in,
                              void* d_out, int out_size, void* d_ws, size_t ws_size,
                              hipStream_t stream) {
    const float* Xr = (const float*)d_in[0];
    const float* Xi = (const float*)d_in[1];
    const float* om = (const float*)d_in[2];
    float* zr = (float*)d_out;
    float* zi = zr + (size_t)B * T * D;   // second tuple output, flat-concatenated

    hopf_scan<<<dim3(B * D / 64), dim3(64), 0, stream>>>(Xr, Xi, om, zr, zi);
}

// Round 2
// 71.776 us; speedup vs baseline: 1.4301x; 1.4301x over previous
//
#include <hip/hip_runtime.h>
#include <hip/hip_bf16.h>

// Hopf oscillator scan: B=32, T=1000, D=512.
// One thread per (b,d) chain, 1000 sequential steps.
// Latency-bound regime (1 wave/CU): software-pipeline with ping-pong
// register buffers, U=20 iters/body => 40 loads (10.2 KB/wave) in flight
// while computing the previous body. Static-indexed arrays only.

#define B 32
#define T 1000
#define D 512
#define DTc 0.001f
#define K_IN 0.005f               // INPUT_SCALER * DT
#define TWO_PI 6.283185307179586f
#define U 20
#define NB (T / U)                // 50 bodies

__device__ __forceinline__ void prefetch(const float* __restrict__ xrp,
                                         const float* __restrict__ xip,
                                         size_t off,
                                         float (&br)[U], float (&bi)[U]) {
#pragma unroll
    for (int i = 0; i < U; ++i) {
        br[i] = xrp[off + (size_t)i * D];
        bi[i] = xip[off + (size_t)i * D];
    }
}

__device__ __forceinline__ void compute_body(const float (&br)[U], const float (&bi)[U],
                                             float* __restrict__ zrp, float* __restrict__ zip,
                                             size_t off, float& r, float& phi,
                                             float& c, float& s, float od) {
#pragma unroll
    for (int i = 0; i < U; ++i) {
        // r_{t+1} = r + ((1 - r^2) r) dt + K*xr*cos(phi_old)
        r = r + ((1.0f - r * r) * r) * DTc + K_IN * br[i] * c;
        // phi_{t+1} = phi + omega dt - K*xi*sin(phi_old)
        phi = phi + od - K_IN * bi[i] * s;
        // sincos(phi_new): this step's output AND next step's input terms
        s = __sinf(phi);
        c = __cosf(phi);
        __builtin_nontemporal_store(r * c, zrp + off + (size_t)i * D);
        __builtin_nontemporal_store(r * s, zip + off + (size_t)i * D);
    }
}

__global__ __launch_bounds__(64) void hopf_scan(
    const float* __restrict__ Xr, const float* __restrict__ Xi,
    const float* __restrict__ om,
    float* __restrict__ zr, float* __restrict__ zi) {
    const int tid = blockIdx.x * 64 + threadIdx.x;   // 0..16383
    const int b = tid >> 9;
    const int d = tid & (D - 1);

    const float od = (om[d] * 10.0f + 0.1f) * TWO_PI * DTc;  // omega*dt in rad

    const size_t base = (size_t)b * (T * D) + d;
    const float* __restrict__ xrp = Xr + base;
    const float* __restrict__ xip = Xi + base;
    float* __restrict__ zrp = zr + base;
    float* __restrict__ zip = zi + base;

    float r = 1.0f, phi = 0.0f, c = 1.0f, s = 0.0f;
    float Ar[U], Ai[U], Br[U], Bi[U];

    prefetch(xrp, xip, 0, Ar, Ai);
    for (int body = 0; body < NB; body += 2) {
        // prefetch body+1 into B while computing body from A
        prefetch(xrp, xip, (size_t)(body + 1) * U * D, Br, Bi);
        compute_body(Ar, Ai, zrp, zip, (size_t)body * U * D, r, phi, c, s, od);
        // prefetch body+2 into A while computing body+1 from B
        if (body + 2 < NB)
            prefetch(xrp, xip, (size_t)(body + 2) * U * D, Ar, Ai);
        compute_body(Br, Bi, zrp, zip, (size_t)(body + 1) * U * D, r, phi, c, s, od);
    }
}

extern "C" void kernel_launch(void* const* d_in, const int* in_sizes, int n_in,
                              void* d_out, int out_size, void* d_ws, size_t ws_size,
                              hipStream_t stream) {
    const float* Xr = (const float*)d_in[0];
    const float* Xi = (const float*)d_in[1];
    const float* om = (const float*)d_in[2];
    float* zr = (float*)d_out;
    float* zi = zr + (size_t)B * T * D;   // tuple output 2, flat-concatenated

    hopf_scan<<<dim3(B * D / 64), dim3(64), 0, stream>>>(Xr, Xi, om, zr, zi);
}

// Round 3
// 59.838 us; speedup vs baseline: 1.7154x; 1.1995x over previous
//
#include <hip/hip_runtime.h>
#include <hip/hip_bf16.h>

// Hopf oscillator scan: B=32, T=1000, D=512.
// One thread per (b,d) chain, 1000 sequential steps. 256 waves = 1 wave/CU:
// latency-bound; all hiding must come from per-wave MLP.
// U=25 ping-pong register buffers; __launch_bounds__(64,1) frees the VGPR
// budget (512 at this occupancy); sched_barrier(0) pins the 50-load prefetch
// cluster BEFORE the compute body so the scheduler cannot sink loads to uses.

#define B 32
#define T 1000
#define D 512
#define DTc 0.001f
#define K_IN 0.005f               // INPUT_SCALER * DT
#define TWO_PI 6.283185307179586f
#define U 25
#define NB (T / U)                // 40 bodies, even -> clean ping-pong

__device__ __forceinline__ void prefetch(const float* __restrict__ xrp,
                                         const float* __restrict__ xip,
                                         size_t off,
                                         float (&br)[U], float (&bi)[U]) {
#pragma unroll
    for (int i = 0; i < U; ++i) {
        br[i] = xrp[off + (size_t)i * D];
        bi[i] = xip[off + (size_t)i * D];
    }
}

__device__ __forceinline__ void compute_body(const float (&br)[U], const float (&bi)[U],
                                             float* __restrict__ zrp, float* __restrict__ zip,
                                             size_t off, float& r, float& phi,
                                             float& c, float& s, float od) {
#pragma unroll
    for (int i = 0; i < U; ++i) {
        // r_{t+1} = r + ((1 - r^2) r) dt + K*xr*cos(phi_old)
        r = r + ((1.0f - r * r) * r) * DTc + K_IN * br[i] * c;
        // phi_{t+1} = phi + omega dt - K*xi*sin(phi_old)
        phi = phi + od - K_IN * bi[i] * s;
        // sincos(phi_new): this step's output AND next step's input terms
        s = __sinf(phi);
        c = __cosf(phi);
        __builtin_nontemporal_store(r * c, zrp + off + (size_t)i * D);
        __builtin_nontemporal_store(r * s, zip + off + (size_t)i * D);
    }
}

__global__ __launch_bounds__(64, 1) void hopf_scan(
    const float* __restrict__ Xr, const float* __restrict__ Xi,
    const float* __restrict__ om,
    float* __restrict__ zr, float* __restrict__ zi) {
    const int tid = blockIdx.x * 64 + threadIdx.x;   // 0..16383
    const int b = tid >> 9;
    const int d = tid & (D - 1);

    const float od = (om[d] * 10.0f + 0.1f) * TWO_PI * DTc;  // omega*dt (rad)

    const size_t base = (size_t)b * (T * D) + d;
    const float* __restrict__ xrp = Xr + base;
    const float* __restrict__ xip = Xi + base;
    float* __restrict__ zrp = zr + base;
    float* __restrict__ zip = zi + base;

    float r = 1.0f, phi = 0.0f, c = 1.0f, s = 0.0f;
    float Ar[U], Ai[U], Br[U], Bi[U];

    prefetch(xrp, xip, 0, Ar, Ai);
    for (int body = 0; body < NB; body += 2) {
        // issue body+1's 50 loads, THEN compute body (loads may not sink past)
        prefetch(xrp, xip, (size_t)(body + 1) * U * D, Br, Bi);
        __builtin_amdgcn_sched_barrier(0);
        compute_body(Ar, Ai, zrp, zip, (size_t)body * U * D, r, phi, c, s, od);

        if (body + 2 < NB)
            prefetch(xrp, xip, (size_t)(body + 2) * U * D, Ar, Ai);
        __builtin_amdgcn_sched_barrier(0);
        compute_body(Br, Bi, zrp, zip, (size_t)(body + 1) * U * D, r, phi, c, s, od);
    }
}

extern "C" void kernel_launch(void* const* d_in, const int* in_sizes, int n_in,
                              void* d_out, int out_size, void* d_ws, size_t ws_size,
                              hipStream_t stream) {
    const float* Xr = (const float*)d_in[0];
    const float* Xi = (const float*)d_in[1];
    const float* om = (const float*)d_in[2];
    float* zr = (float*)d_out;
    float* zi = zr + (size_t)B * T * D;   // tuple output 2, flat-concatenated

    hopf_scan<<<dim3(B * D / 64), dim3(64), 0, stream>>>(Xr, Xi, om, zr, zi);
}